// Round 3
// baseline (801.955 us; speedup 1.0000x reference)
//
#include <hip/hip_runtime.h>
#include <hip/hip_bf16.h>
#include <cstdint>
#include <cstddef>

// Problem constants: B=128, N=196, F=2048, R=1024, H=512
#define Bb   128
#define Nn   196
#define Ff   2048
#define Rr   1024
#define Hh   512
#define Mm   (Bb*Nn)      // 25088

using short8 = __attribute__((ext_vector_type(8))) short;
using f32x4  = __attribute__((ext_vector_type(4))) float;

static __device__ __forceinline__ unsigned short f2bf(float f) {
    unsigned int u = __float_as_uint(f);
    unsigned int r = (u + 0x7FFFu + ((u >> 16) & 1u)) >> 16;
    return (unsigned short)r;
}
static __device__ __forceinline__ float bf2f(unsigned short s) {
    return __uint_as_float(((unsigned int)s) << 16);
}
static __device__ __forceinline__ float sigmf(float x) {
    return 1.0f / (1.0f + expf(-x));
}

// ---------------------------------------------------------------- W_att -> bf16
__global__ void cvt_watt_kernel(const float* __restrict__ W, unsigned short* __restrict__ Wbf) {
    int i = (blockIdx.x * 256 + threadIdx.x) * 4;   // 512*2048 = 1048576 floats
    float4 v = *reinterpret_cast<const float4*>(&W[i]);
    ushort4 u;
    u.x = f2bf(v.x); u.y = f2bf(v.y); u.z = f2bf(v.z); u.w = f2bf(v.w);
    *reinterpret_cast<ushort4*>(&Wbf[i]) = u;
}

// ---------------------------------------------------------------- hb = h @ W_hatt^T + b_att + b_hatt   (128 x 512)
__global__ __launch_bounds__(512) void hb_kernel(
    const float* __restrict__ h, const float* __restrict__ W_hatt,
    const float* __restrict__ b_att, const float* __restrict__ b_hatt,
    float* __restrict__ hb) {
    __shared__ float hs[Rr];
    const int b = blockIdx.x, t = threadIdx.x;
    *reinterpret_cast<float2*>(&hs[t * 2]) =
        *reinterpret_cast<const float2*>(&h[(size_t)b * Rr + t * 2]);
    __syncthreads();
    const float* wr = &W_hatt[(size_t)t * Rr];
    float acc = 0.f;
#pragma unroll 4
    for (int k = 0; k < Rr; k += 4) {
        float4 w4 = *reinterpret_cast<const float4*>(&wr[k]);
        acc += w4.x * hs[k] + w4.y * hs[k + 1] + w4.z * hs[k + 2] + w4.w * hs[k + 3];
    }
    hb[(size_t)b * Hh + t] = acc + b_att[t] + b_hatt[t];
}

// ---------------------------------------------------------------- att GEMM + tanh + w_out dot  -> scores_part[2][25088]
// C[m][n] = sum_k att[m][k] * W_att[n][k]; tile 128M x 256N x 64K, 8 waves.
__global__ __launch_bounds__(512, 2) void gemmB_kernel(
    const float* __restrict__ att, const unsigned short* __restrict__ Wbf,
    const float* __restrict__ hb, const float* __restrict__ w_out,
    float* __restrict__ scores_part) {
    __shared__ __align__(16) unsigned short Asub[128][72];
    __shared__ __align__(16) unsigned short Bsub[256][72];
    __shared__ float s_red[128];

    const int t = threadIdx.x;
    const int bm = blockIdx.x;            // 0..195
    const int bn = blockIdx.y;            // 0..1
    const int m0 = bm * 128;
    const int n0 = bn * 256;
    const int wave = t >> 6, lane = t & 63;
    const int l15 = lane & 15, lhi = lane >> 4;
    const int wm = wave >> 2, wn = wave & 3;     // 2 x 4 wave grid -> 64M x 64N per wave

    if (t < 128) s_red[t] = 0.f;

    f32x4 acc[4][4] = {};

    for (int k0 = 0; k0 < Ff; k0 += 64) {
        __syncthreads();
        // stage A: 128 rows x 64 k, fp32 -> bf16
#pragma unroll
        for (int i = 0; i < 4; ++i) {
            int idx = i * 512 + t;
            int row = idx >> 4, kq = idx & 15;
            float4 v = *reinterpret_cast<const float4*>(
                &att[(size_t)(m0 + row) * Ff + k0 + kq * 4]);
            ushort4 u;
            u.x = f2bf(v.x); u.y = f2bf(v.y); u.z = f2bf(v.z); u.w = f2bf(v.w);
            *reinterpret_cast<ushort4*>(&Asub[row][kq * 4]) = u;
        }
        // stage B: 256 rows x 64 k, already bf16
#pragma unroll
        for (int i = 0; i < 4; ++i) {
            int idx = i * 512 + t;
            int row = idx >> 3, kb = idx & 7;
            int4 v = *reinterpret_cast<const int4*>(
                &Wbf[(size_t)(n0 + row) * Ff + k0 + kb * 8]);
            *reinterpret_cast<int4*>(&Bsub[row][kb * 8]) = v;
        }
        __syncthreads();
#pragma unroll
        for (int kk = 0; kk < 2; ++kk) {
            short8 a[4], b[4];
#pragma unroll
            for (int mi = 0; mi < 4; ++mi)
                a[mi] = *reinterpret_cast<const short8*>(
                    &Asub[wm * 64 + mi * 16 + l15][kk * 32 + lhi * 8]);
#pragma unroll
            for (int ni = 0; ni < 4; ++ni)
                b[ni] = *reinterpret_cast<const short8*>(
                    &Bsub[wn * 64 + ni * 16 + l15][kk * 32 + lhi * 8]);
#pragma unroll
            for (int mi = 0; mi < 4; ++mi)
#pragma unroll
                for (int ni = 0; ni < 4; ++ni)
                    acc[mi][ni] = __builtin_amdgcn_mfma_f32_16x16x32_bf16(
                        a[mi], b[ni], acc[mi][ni], 0, 0, 0);
        }
    }

    // epilogue: tanh(C + hb) * w_out, reduce over the block's 256 columns
#pragma unroll
    for (int mi = 0; mi < 4; ++mi) {
#pragma unroll
        for (int r = 0; r < 4; ++r) {
            int m_local = wm * 64 + mi * 16 + lhi * 4 + r;
            int m = m0 + m_local;
            int bidx = m / Nn;
            float sum = 0.f;
#pragma unroll
            for (int ni = 0; ni < 4; ++ni) {
                int n = n0 + wn * 64 + ni * 16 + l15;
                float v = acc[mi][ni][r] + hb[(size_t)bidx * Hh + n];
                sum += tanhf(v) * w_out[n];
            }
            sum += __shfl_xor(sum, 1);
            sum += __shfl_xor(sum, 2);
            sum += __shfl_xor(sum, 4);
            sum += __shfl_xor(sum, 8);
            if (l15 == 0) atomicAdd(&s_red[m_local], sum);
        }
    }
    __syncthreads();
    if (t < 128) scores_part[(size_t)bn * Mm + m0 + t] = s_red[t];
}

// ---------------------------------------------------------------- softmax over N=196 per batch
__global__ void softmax_kernel(const float* __restrict__ sp, float* __restrict__ conv) {
    __shared__ float redm[4];
    __shared__ float reds[4];
    const int b = blockIdx.x, t = threadIdx.x;   // 256 threads
    float s = -1e30f;
    if (t < Nn) s = sp[(size_t)b * Nn + t] + sp[(size_t)Mm + b * Nn + t];
    float v = s;
#pragma unroll
    for (int o = 1; o < 64; o <<= 1) v = fmaxf(v, __shfl_xor(v, o));
    if ((t & 63) == 0) redm[t >> 6] = v;
    __syncthreads();
    float mx = fmaxf(fmaxf(redm[0], redm[1]), fmaxf(redm[2], redm[3]));
    float e = (t < Nn) ? expf(s - mx) : 0.f;
    float sv = e;
#pragma unroll
    for (int o = 1; o < 64; o <<= 1) sv += __shfl_xor(sv, o);
    if ((t & 63) == 0) reds[t >> 6] = sv;
    __syncthreads();
    float tot = reds[0] + reds[1] + reds[2] + reds[3];
    if (t < Nn) conv[(size_t)b * Nn + t] = e / tot;
}

// ---------------------------------------------------------------- z partials: z_part[ns][b][f] = sum_{n in chunk} w*att
__global__ __launch_bounds__(256) void zpart_kernel(
    const float* __restrict__ att, const float* __restrict__ conv,
    float* __restrict__ zp) {
    const int fc = blockIdx.x;   // 0..1
    const int b  = blockIdx.y;   // 0..127
    const int ns = blockIdx.z;   // 0..3
    const int t  = threadIdx.x;
    const int f  = fc * 1024 + t * 4;
    const int nbeg = ns * 49;
    const float* ab = &att[((size_t)b * Nn + nbeg) * Ff + f];
    const float* cw = &conv[(size_t)b * Nn + nbeg];
    float4 acc = {0.f, 0.f, 0.f, 0.f};
#pragma unroll 7
    for (int n = 0; n < 49; ++n) {
        float w = cw[n];
        float4 a = *reinterpret_cast<const float4*>(&ab[(size_t)n * Ff]);
        acc.x += w * a.x; acc.y += w * a.y; acc.z += w * a.z; acc.w += w * a.w;
    }
    *reinterpret_cast<float4*>(&zp[((size_t)ns * Bb + b) * Ff + f]) = acc;
}

__global__ void zcomb_kernel(const float* __restrict__ zp, float* __restrict__ z) {
    const size_t i = ((size_t)blockIdx.x * 256 + threadIdx.x) * 4;   // 262144 floats
    float4 a = *reinterpret_cast<const float4*>(&zp[i]);
    float4 b = *reinterpret_cast<const float4*>(&zp[262144 + i]);
    float4 c = *reinterpret_cast<const float4*>(&zp[524288 + i]);
    float4 d = *reinterpret_cast<const float4*>(&zp[786432 + i]);
    float4 o;
    o.x = a.x + b.x + c.x + d.x; o.y = a.y + b.y + c.y + d.y;
    o.z = a.z + b.z + c.z + d.z; o.w = a.w + b.w + c.w + d.w;
    *reinterpret_cast<float4*>(&z[i]) = o;
}

// ---------------------------------------------------------------- LSTM GEMM: [h|z](128x3072) @ [W_h2h|W_z2h]^T (4096x3072)
// split-bf16 (hi/lo) for ~fp32 accuracy. tile 128M x 32N x 64K, 4 waves.
__global__ __launch_bounds__(256, 2) void gemm2_kernel(
    const float* __restrict__ h, const float* __restrict__ z,
    const float* __restrict__ Wh2h, const float* __restrict__ Wz2h,
    const float* __restrict__ bh2h, const float* __restrict__ bz2h,
    float* __restrict__ S) {
    __shared__ __align__(16) unsigned short Ah[128][72];
    __shared__ __align__(16) unsigned short Al[128][72];
    __shared__ __align__(16) unsigned short Bh[32][72];
    __shared__ __align__(16) unsigned short Bl[32][72];

    const int t = threadIdx.x;
    const int n0 = blockIdx.x * 32;                 // 128 blocks
    const int wave = t >> 6, lane = t & 63;
    const int l15 = lane & 15, lhi = lane >> 4;
    const int wm = wave >> 1, wn = wave & 1;        // wave tile 64M x 16N

    f32x4 acc[4] = {};

    for (int k0 = 0; k0 < 3072; k0 += 64) {
        __syncthreads();
        const bool hpart = (k0 < 1024);
        // stage A: 128 x 64 fp32 -> hi/lo bf16
#pragma unroll
        for (int i = 0; i < 8; ++i) {
            int idx = i * 256 + t;
            int row = idx >> 4, kq = idx & 15;
            int kg = k0 + kq * 4;
            const float* src = hpart ? &h[(size_t)row * Rr + kg]
                                     : &z[(size_t)row * Ff + (kg - 1024)];
            float4 v = *reinterpret_cast<const float4*>(src);
            ushort4 uh, ul;
            uh.x = f2bf(v.x); ul.x = f2bf(v.x - bf2f(uh.x));
            uh.y = f2bf(v.y); ul.y = f2bf(v.y - bf2f(uh.y));
            uh.z = f2bf(v.z); ul.z = f2bf(v.z - bf2f(uh.z));
            uh.w = f2bf(v.w); ul.w = f2bf(v.w - bf2f(uh.w));
            *reinterpret_cast<ushort4*>(&Ah[row][kq * 4]) = uh;
            *reinterpret_cast<ushort4*>(&Al[row][kq * 4]) = ul;
        }
        // stage B: 32 x 64 fp32 -> hi/lo bf16
#pragma unroll
        for (int i = 0; i < 2; ++i) {
            int idx = i * 256 + t;
            int row = idx >> 4, kq = idx & 15;
            int kg = k0 + kq * 4;
            int n = n0 + row;
            const float* src = hpart ? &Wh2h[(size_t)n * Rr + kg]
                                     : &Wz2h[(size_t)n * Ff + (kg - 1024)];
            float4 v = *reinterpret_cast<const float4*>(src);
            ushort4 uh, ul;
            uh.x = f2bf(v.x); ul.x = f2bf(v.x - bf2f(uh.x));
            uh.y = f2bf(v.y); ul.y = f2bf(v.y - bf2f(uh.y));
            uh.z = f2bf(v.z); ul.z = f2bf(v.z - bf2f(uh.z));
            uh.w = f2bf(v.w); ul.w = f2bf(v.w - bf2f(uh.w));
            *reinterpret_cast<ushort4*>(&Bh[row][kq * 4]) = uh;
            *reinterpret_cast<ushort4*>(&Bl[row][kq * 4]) = ul;
        }
        __syncthreads();
#pragma unroll
        for (int kk = 0; kk < 2; ++kk) {
            short8 bhf = *reinterpret_cast<const short8*>(
                &Bh[wn * 16 + l15][kk * 32 + lhi * 8]);
            short8 blf = *reinterpret_cast<const short8*>(
                &Bl[wn * 16 + l15][kk * 32 + lhi * 8]);
#pragma unroll
            for (int mi = 0; mi < 4; ++mi) {
                short8 ahf = *reinterpret_cast<const short8*>(
                    &Ah[wm * 64 + mi * 16 + l15][kk * 32 + lhi * 8]);
                short8 alf = *reinterpret_cast<const short8*>(
                    &Al[wm * 64 + mi * 16 + l15][kk * 32 + lhi * 8]);
                acc[mi] = __builtin_amdgcn_mfma_f32_16x16x32_bf16(ahf, bhf, acc[mi], 0, 0, 0);
                acc[mi] = __builtin_amdgcn_mfma_f32_16x16x32_bf16(ahf, blf, acc[mi], 0, 0, 0);
                acc[mi] = __builtin_amdgcn_mfma_f32_16x16x32_bf16(alf, bhf, acc[mi], 0, 0, 0);
            }
        }
    }
    const int n = n0 + wn * 16 + l15;
    const float bias = bh2h[n] + bz2h[n];
#pragma unroll
    for (int mi = 0; mi < 4; ++mi)
#pragma unroll
        for (int r = 0; r < 4; ++r) {
            int brow = wm * 64 + mi * 16 + lhi * 4 + r;
            S[(size_t)brow * 4096 + n] = acc[mi][r] + bias;
        }
}

// ---------------------------------------------------------------- LSTM gates
__global__ void lstm_kernel(const float* __restrict__ S, const float* __restrict__ c,
                            float* __restrict__ out) {
    const int t = blockIdx.x * 256 + threadIdx.x;  // 131072
    const int b = t >> 10, r = t & 1023;
    const float* Sb = &S[(size_t)b * 4096];
    float ig = sigmf(Sb[r]);
    float fg = sigmf(Sb[1024 + r]);
    float og = sigmf(Sb[2048 + r]);
    float gt = tanhf(Sb[3072 + r]);
    float nc = fg * c[t] + ig * gt;
    float nh = og * tanhf(nc);
    out[t] = nh;
    out[131072 + t] = nc;
}

// ================================================================ launch
extern "C" void kernel_launch(void* const* d_in, const int* in_sizes, int n_in,
                              void* d_out, int out_size, void* d_ws, size_t ws_size,
                              hipStream_t stream) {
    const float* att     = (const float*)d_in[0];
    const float* h       = (const float*)d_in[3];
    const float* c       = (const float*)d_in[4];
    const float* W_att   = (const float*)d_in[5];
    const float* b_att   = (const float*)d_in[6];
    const float* W_hatt  = (const float*)d_in[7];
    const float* b_hatt  = (const float*)d_in[8];
    const float* w_out   = (const float*)d_in[9];
    const float* W_h2h   = (const float*)d_in[11];
    const float* b_h2h   = (const float*)d_in[12];
    const float* W_z2h   = (const float*)d_in[13];
    const float* b_z2h   = (const float*)d_in[14];
    float* out = (float*)d_out;

    char* ws = (char*)d_ws;
    size_t o = 0;
    unsigned short* Wbf = (unsigned short*)(ws + o); o += (size_t)Hh * Ff * 2;        // 2 MB
    float* hb           = (float*)(ws + o);          o += (size_t)Bb * Hh * 4;        // 256 KB
    float* sp           = (float*)(ws + o);          o += (size_t)2 * Mm * 4;         // 200 KB
    float* conv         = (float*)(ws + o);          o += (size_t)Bb * Nn * 4;        // 100 KB
    float* zp           = (float*)(ws + o);          o += (size_t)4 * Bb * Ff * 4;    // 4 MB
    float* z            = (float*)(ws + o);          o += (size_t)Bb * Ff * 4;        // 1 MB
    float* S            = (float*)(ws + o);          o += (size_t)Bb * 4096 * 4;      // 2 MB

    cvt_watt_kernel<<<1024, 256, 0, stream>>>(W_att, Wbf);
    hb_kernel<<<Bb, 512, 0, stream>>>(h, W_hatt, b_att, b_hatt, hb);
    gemmB_kernel<<<dim3(Mm / 128, 2), 512, 0, stream>>>(att, Wbf, hb, w_out, sp);
    softmax_kernel<<<Bb, 256, 0, stream>>>(sp, conv);
    zpart_kernel<<<dim3(2, Bb, 4), 256, 0, stream>>>(att, conv, zp);
    zcomb_kernel<<<256, 256, 0, stream>>>(zp, z);
    gemm2_kernel<<<128, 256, 0, stream>>>(h, z, W_h2h, W_z2h, b_h2h, b_z2h, S);
    lstm_kernel<<<512, 256, 0, stream>>>(S, c, out);
}

// Round 5
// 736.711 us; speedup vs baseline: 1.0886x; 1.0886x over previous
//
#include <hip/hip_runtime.h>
#include <hip/hip_bf16.h>
#include <cstdint>
#include <cstddef>

// Problem constants: B=128, N=196, F=2048, R=1024, H=512
#define Bb   128
#define Nn   196
#define Ff   2048
#define Rr   1024
#define Hh   512
#define Mm   (Bb*Nn)      // 25088

using short8 = __attribute__((ext_vector_type(8))) short;
using f32x4  = __attribute__((ext_vector_type(4))) float;

typedef const __attribute__((address_space(1))) void cas1_void;
typedef __attribute__((address_space(3))) void as3_void;

static __device__ __forceinline__ unsigned short f2bf(float f) {
    unsigned int u = __float_as_uint(f);
    unsigned int r = (u + 0x7FFFu + ((u >> 16) & 1u)) >> 16;
    return (unsigned short)r;
}
static __device__ __forceinline__ float bf2f(unsigned short s) {
    return __uint_as_float(((unsigned int)s) << 16);
}
static __device__ __forceinline__ float sigmf(float x) {
    return 1.0f / (1.0f + expf(-x));
}

// ---------------------------------------------------------------- W_att -> bf16
__global__ void cvt_watt_kernel(const float* __restrict__ W, unsigned short* __restrict__ Wbf) {
    int i = (blockIdx.x * 256 + threadIdx.x) * 4;   // 512*2048 = 1048576 floats
    float4 v = *reinterpret_cast<const float4*>(&W[i]);
    ushort4 u;
    u.x = f2bf(v.x); u.y = f2bf(v.y); u.z = f2bf(v.z); u.w = f2bf(v.w);
    *reinterpret_cast<ushort4*>(&Wbf[i]) = u;
}

// ---------------------------------------------------------------- hb = h @ W_hatt^T + b_att + b_hatt   (128 x 512)
__global__ __launch_bounds__(512) void hb_kernel(
    const float* __restrict__ h, const float* __restrict__ W_hatt,
    const float* __restrict__ b_att, const float* __restrict__ b_hatt,
    float* __restrict__ hb) {
    __shared__ float hs[Rr];
    const int b = blockIdx.x, t = threadIdx.x;
    *reinterpret_cast<float2*>(&hs[t * 2]) =
        *reinterpret_cast<const float2*>(&h[(size_t)b * Rr + t * 2]);
    __syncthreads();
    const float* wr = &W_hatt[(size_t)t * Rr];
    float acc = 0.f;
#pragma unroll 4
    for (int k = 0; k < Rr; k += 4) {
        float4 w4 = *reinterpret_cast<const float4*>(&wr[k]);
        acc += w4.x * hs[k] + w4.y * hs[k + 1] + w4.z * hs[k + 2] + w4.w * hs[k + 3];
    }
    hb[(size_t)b * Hh + t] = acc + b_att[t] + b_hatt[t];
}

// ---------------------------------------------------------------- att GEMM + tanh + w_out dot -> scores_part[4][25088]
// C[m][n] = sum_k att[m][k]*W_att[n][k]. Tile 128M x 128N x 64K, 256 thr (4 waves 2x2).
// B staged via global_load_lds (16B) with XOR chunk swizzle (src chunk = j ^ (row&7));
// A reg-staged fp32->bf16 into 72-padded LDS (2-way conflicts only = free).
__global__ __launch_bounds__(256, 3) void gemmB_kernel(
    const float* __restrict__ att, const unsigned short* __restrict__ Wbf,
    const float* __restrict__ hb, const float* __restrict__ w_out,
    float* __restrict__ scores_part) {
    __shared__ __align__(16) unsigned short Asub[128][72];
    __shared__ __align__(16) unsigned short Bsub[128 * 64];   // linear rows of 128B, chunk-swizzled
    __shared__ float s_red[128];

    const int t = threadIdx.x;
    const int m0 = blockIdx.x * 128;          // 196 m-blocks
    const int n0 = blockIdx.y * 128;          // 4 n-blocks
    const int wave = t >> 6, lane = t & 63;
    const int l15 = lane & 15, lhi = lane >> 4;
    const int wm = wave >> 1, wn = wave & 1;  // 2x2 wave grid, 64x64 per wave

    if (t < 128) s_red[t] = 0.f;

    f32x4 acc[4][4] = {};

    for (int k0 = 0; k0 < Ff; k0 += 64) {
        __syncthreads();
        // ---- B: async global->LDS, pre-swizzled per-lane source, linear LDS dest
#pragma unroll
        for (int i = 0; i < 4; ++i) {
            int idx = i * 256 + t;
            int row = idx >> 3, p = idx & 7;               // phys 16B chunk p in row
            const unsigned short* src =
                &Wbf[(size_t)(n0 + row) * Ff + k0 + ((p ^ (row & 7)) << 3)];
            __builtin_amdgcn_global_load_lds(
                (cas1_void*)src,
                (as3_void*)&Bsub[i * 2048 + wave * 512], 16, 0, 0);
        }
        // ---- A: fp32 -> bf16 reg-staged
#pragma unroll
        for (int i = 0; i < 8; ++i) {
            int idx = i * 256 + t;
            int row = idx >> 4, kq = idx & 15;
            float4 v = *reinterpret_cast<const float4*>(
                &att[(size_t)(m0 + row) * Ff + k0 + kq * 4]);
            ushort4 u;
            u.x = f2bf(v.x); u.y = f2bf(v.y); u.z = f2bf(v.z); u.w = f2bf(v.w);
            *reinterpret_cast<ushort4*>(&Asub[row][kq * 4]) = u;
        }
        __syncthreads();
#pragma unroll
        for (int kk = 0; kk < 2; ++kk) {
            short8 a[4], b[4];
#pragma unroll
            for (int mi = 0; mi < 4; ++mi)
                a[mi] = *reinterpret_cast<const short8*>(
                    &Asub[wm * 64 + mi * 16 + l15][kk * 32 + lhi * 8]);
#pragma unroll
            for (int ni = 0; ni < 4; ++ni) {
                int row = wn * 64 + ni * 16 + l15;
                int ch = (kk * 4 + lhi) ^ (row & 7);       // un-swizzle on read
                b[ni] = *reinterpret_cast<const short8*>(&Bsub[row * 64 + ch * 8]);
            }
#pragma unroll
            for (int mi = 0; mi < 4; ++mi)
#pragma unroll
                for (int ni = 0; ni < 4; ++ni)
                    acc[mi][ni] = __builtin_amdgcn_mfma_f32_16x16x32_bf16(
                        a[mi], b[ni], acc[mi][ni], 0, 0, 0);
        }
    }

    // epilogue: tanh(C + hb) * w_out, reduce the block's 128 columns
#pragma unroll
    for (int mi = 0; mi < 4; ++mi) {
#pragma unroll
        for (int r = 0; r < 4; ++r) {
            int m_local = wm * 64 + mi * 16 + lhi * 4 + r;
            int m = m0 + m_local;
            int bidx = m / Nn;
            float sum = 0.f;
#pragma unroll
            for (int ni = 0; ni < 4; ++ni) {
                int n = n0 + wn * 64 + ni * 16 + l15;
                float v = acc[mi][ni][r] + hb[(size_t)bidx * Hh + n];
                sum += tanhf(v) * w_out[n];
            }
            sum += __shfl_xor(sum, 1);
            sum += __shfl_xor(sum, 2);
            sum += __shfl_xor(sum, 4);
            sum += __shfl_xor(sum, 8);
            if (l15 == 0) atomicAdd(&s_red[m_local], sum);
        }
    }
    __syncthreads();
    if (t < 128) scores_part[(size_t)blockIdx.y * Mm + m0 + t] = s_red[t];
}

// ---------------------------------------------------------------- softmax over N=196 per batch (sums 4 n-partials)
__global__ void softmax_kernel(const float* __restrict__ sp, float* __restrict__ conv) {
    __shared__ float redm[4];
    __shared__ float reds[4];
    const int b = blockIdx.x, t = threadIdx.x;   // 256 threads
    float s = -1e30f;
    if (t < Nn) {
        size_t i = (size_t)b * Nn + t;
        s = sp[i] + sp[Mm + i] + sp[2 * (size_t)Mm + i] + sp[3 * (size_t)Mm + i];
    }
    float v = s;
#pragma unroll
    for (int o = 1; o < 64; o <<= 1) v = fmaxf(v, __shfl_xor(v, o));
    if ((t & 63) == 0) redm[t >> 6] = v;
    __syncthreads();
    float mx = fmaxf(fmaxf(redm[0], redm[1]), fmaxf(redm[2], redm[3]));
    float e = (t < Nn) ? expf(s - mx) : 0.f;
    float sv = e;
#pragma unroll
    for (int o = 1; o < 64; o <<= 1) sv += __shfl_xor(sv, o);
    if ((t & 63) == 0) reds[t >> 6] = sv;
    __syncthreads();
    float tot = reds[0] + reds[1] + reds[2] + reds[3];
    if (t < Nn) conv[(size_t)b * Nn + t] = e / tot;
}

// ---------------------------------------------------------------- z partials: z_part[ns][b][f] = sum_{n in chunk} w*att
__global__ __launch_bounds__(256) void zpart_kernel(
    const float* __restrict__ att, const float* __restrict__ conv,
    float* __restrict__ zp) {
    const int fc = blockIdx.x;   // 0..1
    const int b  = blockIdx.y;   // 0..127
    const int ns = blockIdx.z;   // 0..3
    const int t  = threadIdx.x;
    const int f  = fc * 1024 + t * 4;
    const int nbeg = ns * 49;
    const float* ab = &att[((size_t)b * Nn + nbeg) * Ff + f];
    const float* cw = &conv[(size_t)b * Nn + nbeg];
    float4 acc = {0.f, 0.f, 0.f, 0.f};
#pragma unroll 7
    for (int n = 0; n < 49; ++n) {
        float w = cw[n];
        float4 a = *reinterpret_cast<const float4*>(&ab[(size_t)n * Ff]);
        acc.x += w * a.x; acc.y += w * a.y; acc.z += w * a.z; acc.w += w * a.w;
    }
    *reinterpret_cast<float4*>(&zp[((size_t)ns * Bb + b) * Ff + f]) = acc;
}

__global__ void zcomb_kernel(const float* __restrict__ zp, float* __restrict__ z) {
    const size_t i = ((size_t)blockIdx.x * 256 + threadIdx.x) * 4;   // 262144 floats
    float4 a = *reinterpret_cast<const float4*>(&zp[i]);
    float4 b = *reinterpret_cast<const float4*>(&zp[262144 + i]);
    float4 c = *reinterpret_cast<const float4*>(&zp[524288 + i]);
    float4 d = *reinterpret_cast<const float4*>(&zp[786432 + i]);
    float4 o;
    o.x = a.x + b.x + c.x + d.x; o.y = a.y + b.y + c.y + d.y;
    o.z = a.z + b.z + c.z + d.z; o.w = a.w + b.w + c.w + d.w;
    *reinterpret_cast<float4*>(&z[i]) = o;
}

// ---------------------------------------------------------------- [h|z] -> hi/lo bf16, once (kills 128x duplicated cvt in gemm2)
__global__ void cvt_hz_kernel(const float* __restrict__ h, const float* __restrict__ z,
                              unsigned short* __restrict__ hzh, unsigned short* __restrict__ hzl) {
    int i = blockIdx.x * 256 + threadIdx.x;      // 98304 threads -> 384 blocks
    int e = i * 4;
    int row = e / 3072, col = e - row * 3072;    // 4-chunks never straddle the 1024 boundary
    const float* src = (col < 1024) ? &h[(size_t)row * Rr + col]
                                    : &z[(size_t)row * Ff + (col - 1024)];
    float4 v = *reinterpret_cast<const float4*>(src);
    ushort4 uh, ul;
    uh.x = f2bf(v.x); ul.x = f2bf(v.x - bf2f(uh.x));
    uh.y = f2bf(v.y); ul.y = f2bf(v.y - bf2f(uh.y));
    uh.z = f2bf(v.z); ul.z = f2bf(v.z - bf2f(uh.z));
    uh.w = f2bf(v.w); ul.w = f2bf(v.w - bf2f(uh.w));
    *reinterpret_cast<ushort4*>(&hzh[e]) = uh;
    *reinterpret_cast<ushort4*>(&hzl[e]) = ul;
}

// ---------------------------------------------------------------- LSTM GEMM: [h|z](128x3072) @ [W_h2h|W_z2h]^T (4096x3072)
// split-bf16 (hi/lo). A pre-converted (pure int4 copy staging); B fp32->hi/lo per block (distinct cols, no dup).
__global__ __launch_bounds__(256, 2) void gemm2_kernel(
    const unsigned short* __restrict__ hzh, const unsigned short* __restrict__ hzl,
    const float* __restrict__ Wh2h, const float* __restrict__ Wz2h,
    const float* __restrict__ bh2h, const float* __restrict__ bz2h,
    float* __restrict__ S) {
    __shared__ __align__(16) unsigned short Ah[128][72];
    __shared__ __align__(16) unsigned short Al[128][72];
    __shared__ __align__(16) unsigned short Bh[32][72];
    __shared__ __align__(16) unsigned short Bl[32][72];

    const int t = threadIdx.x;
    const int n0 = blockIdx.x * 32;                 // 128 blocks
    const int wave = t >> 6, lane = t & 63;
    const int l15 = lane & 15, lhi = lane >> 4;
    const int wm = wave >> 1, wn = wave & 1;        // wave tile 64M x 16N

    f32x4 acc[4] = {};

    for (int k0 = 0; k0 < 3072; k0 += 64) {
        __syncthreads();
        // stage A: pure bf16 copies
#pragma unroll
        for (int i = 0; i < 4; ++i) {
            int idx = i * 256 + t;
            int row = idx >> 3, k8 = idx & 7;
            *reinterpret_cast<int4*>(&Ah[row][k8 * 8]) =
                *reinterpret_cast<const int4*>(&hzh[(size_t)row * 3072 + k0 + k8 * 8]);
            *reinterpret_cast<int4*>(&Al[row][k8 * 8]) =
                *reinterpret_cast<const int4*>(&hzl[(size_t)row * 3072 + k0 + k8 * 8]);
        }
        // stage B: 32 x 64 fp32 -> hi/lo bf16
        const bool hpart = (k0 < 1024);
#pragma unroll
        for (int i = 0; i < 2; ++i) {
            int idx = i * 256 + t;
            int row = idx >> 4, kq = idx & 15;
            int kg = k0 + kq * 4;
            int n = n0 + row;
            const float* src = hpart ? &Wh2h[(size_t)n * Rr + kg]
                                     : &Wz2h[(size_t)n * Ff + (kg - 1024)];
            float4 v = *reinterpret_cast<const float4*>(src);
            ushort4 uh, ul;
            uh.x = f2bf(v.x); ul.x = f2bf(v.x - bf2f(uh.x));
            uh.y = f2bf(v.y); ul.y = f2bf(v.y - bf2f(uh.y));
            uh.z = f2bf(v.z); ul.z = f2bf(v.z - bf2f(uh.z));
            uh.w = f2bf(v.w); ul.w = f2bf(v.w - bf2f(uh.w));
            *reinterpret_cast<ushort4*>(&Bh[row][kq * 4]) = uh;
            *reinterpret_cast<ushort4*>(&Bl[row][kq * 4]) = ul;
        }
        __syncthreads();
#pragma unroll
        for (int kk = 0; kk < 2; ++kk) {
            short8 bhf = *reinterpret_cast<const short8*>(
                &Bh[wn * 16 + l15][kk * 32 + lhi * 8]);
            short8 blf = *reinterpret_cast<const short8*>(
                &Bl[wn * 16 + l15][kk * 32 + lhi * 8]);
#pragma unroll
            for (int mi = 0; mi < 4; ++mi) {
                short8 ahf = *reinterpret_cast<const short8*>(
                    &Ah[wm * 64 + mi * 16 + l15][kk * 32 + lhi * 8]);
                short8 alf = *reinterpret_cast<const short8*>(
                    &Al[wm * 64 + mi * 16 + l15][kk * 32 + lhi * 8]);
                acc[mi] = __builtin_amdgcn_mfma_f32_16x16x32_bf16(ahf, bhf, acc[mi], 0, 0, 0);
                acc[mi] = __builtin_amdgcn_mfma_f32_16x16x32_bf16(ahf, blf, acc[mi], 0, 0, 0);
                acc[mi] = __builtin_amdgcn_mfma_f32_16x16x32_bf16(alf, bhf, acc[mi], 0, 0, 0);
            }
        }
    }
    const int n = n0 + wn * 16 + l15;
    const float bias = bh2h[n] + bz2h[n];
#pragma unroll
    for (int mi = 0; mi < 4; ++mi)
#pragma unroll
        for (int r = 0; r < 4; ++r) {
            int brow = wm * 64 + mi * 16 + lhi * 4 + r;
            S[(size_t)brow * 4096 + n] = acc[mi][r] + bias;
        }
}

// ---------------------------------------------------------------- LSTM gates
__global__ void lstm_kernel(const float* __restrict__ S, const float* __restrict__ c,
                            float* __restrict__ out) {
    const int t = blockIdx.x * 256 + threadIdx.x;  // 131072
    const int b = t >> 10, r = t & 1023;
    const float* Sb = &S[(size_t)b * 4096];
    float ig = sigmf(Sb[r]);
    float fg = sigmf(Sb[1024 + r]);
    float og = sigmf(Sb[2048 + r]);
    float gt = tanhf(Sb[3072 + r]);
    float nc = fg * c[t] + ig * gt;
    float nh = og * tanhf(nc);
    out[t] = nh;
    out[131072 + t] = nc;
}

// ================================================================ launch
extern "C" void kernel_launch(void* const* d_in, const int* in_sizes, int n_in,
                              void* d_out, int out_size, void* d_ws, size_t ws_size,
                              hipStream_t stream) {
    const float* att     = (const float*)d_in[0];
    const float* h       = (const float*)d_in[3];
    const float* c       = (const float*)d_in[4];
    const float* W_att   = (const float*)d_in[5];
    const float* b_att   = (const float*)d_in[6];
    const float* W_hatt  = (const float*)d_in[7];
    const float* b_hatt  = (const float*)d_in[8];
    const float* w_out   = (const float*)d_in[9];
    const float* W_h2h   = (const float*)d_in[11];
    const float* b_h2h   = (const float*)d_in[12];
    const float* W_z2h   = (const float*)d_in[13];
    const float* b_z2h   = (const float*)d_in[14];
    float* out = (float*)d_out;

    char* ws = (char*)d_ws;
    size_t o = 0;
    unsigned short* Wbf = (unsigned short*)(ws + o); o += (size_t)Hh * Ff * 2;        // 2 MB
    float* hb           = (float*)(ws + o);          o += (size_t)Bb * Hh * 4;        // 256 KB
    float* sp           = (float*)(ws + o);          o += (size_t)4 * Mm * 4;         // 400 KB
    float* conv         = (float*)(ws + o);          o += (size_t)Bb * Nn * 4;        // 100 KB
    float* zp           = (float*)(ws + o);          o += (size_t)4 * Bb * Ff * 4;    // 4 MB
    float* z            = (float*)(ws + o);          o += (size_t)Bb * Ff * 4;        // 1 MB
    float* S            = (float*)(ws + o);          o += (size_t)Bb * 4096 * 4;      // 2 MB
    unsigned short* hzh = (unsigned short*)(ws + o); o += (size_t)Bb * 3072 * 2;      // 768 KB
    unsigned short* hzl = (unsigned short*)(ws + o); o += (size_t)Bb * 3072 * 2;      // 768 KB

    cvt_watt_kernel<<<1024, 256, 0, stream>>>(W_att, Wbf);
    hb_kernel<<<Bb, 512, 0, stream>>>(h, W_hatt, b_att, b_hatt, hb);
    gemmB_kernel<<<dim3(Mm / 128, 4), 256, 0, stream>>>(att, Wbf, hb, w_out, sp);
    softmax_kernel<<<Bb, 256, 0, stream>>>(sp, conv);
    zpart_kernel<<<dim3(2, Bb, 4), 256, 0, stream>>>(att, conv, zp);
    zcomb_kernel<<<256, 256, 0, stream>>>(zp, z);
    cvt_hz_kernel<<<384, 256, 0, stream>>>(h, z, hzh, hzl);
    gemm2_kernel<<<128, 256, 0, stream>>>(hzh, hzl, W_h2h, W_z2h, b_h2h, b_z2h, S);
    lstm_kernel<<<512, 256, 0, stream>>>(S, c, out);
}

// Round 7
// 647.080 us; speedup vs baseline: 1.2393x; 1.1385x over previous
//
#include <hip/hip_runtime.h>
#include <hip/hip_bf16.h>
#include <cstdint>
#include <cstddef>

// Problem constants: B=128, N=196, F=2048, R=1024, H=512
#define Bb   128
#define Nn   196
#define Ff   2048
#define Rr   1024
#define Hh   512
#define Mm   (Bb*Nn)      // 25088
#define KT   32           // K-tiles of 64 in F

using short8   = __attribute__((ext_vector_type(8))) short;
using ushort8v = __attribute__((ext_vector_type(8))) unsigned short;
using f32x4    = __attribute__((ext_vector_type(4))) float;

typedef const __attribute__((address_space(1))) void cas1_void;
typedef __attribute__((address_space(3))) void as3_void;

static __device__ __forceinline__ unsigned short f2bf(float f) {
    unsigned int u = __float_as_uint(f);
    unsigned int r = (u + 0x7FFFu + ((u >> 16) & 1u)) >> 16;
    return (unsigned short)r;
}
static __device__ __forceinline__ float bf2f(unsigned short s) {
    return __uint_as_float(((unsigned int)s) << 16);
}
static __device__ __forceinline__ float sigmf(float x) {
    return 1.0f / (1.0f + expf(-x));
}

// ---------------------------------------------------------------- W_att -> bf16, tiled [4][32][128][64] + chunk-XOR swizzle
__global__ void cvt_watt_kernel(const float* __restrict__ W, unsigned short* __restrict__ wbt) {
    int g = blockIdx.x * 256 + threadIdx.x;   // 131072 threads, 8 cols each
    int n = g >> 8;
    int k = (g & 255) * 8;
    float4 v0 = *reinterpret_cast<const float4*>(&W[(size_t)n * Ff + k]);
    float4 v1 = *reinterpret_cast<const float4*>(&W[(size_t)n * Ff + k + 4]);
    ushort8v u;
    u[0]=f2bf(v0.x); u[1]=f2bf(v0.y); u[2]=f2bf(v0.z); u[3]=f2bf(v0.w);
    u[4]=f2bf(v1.x); u[5]=f2bf(v1.y); u[6]=f2bf(v1.z); u[7]=f2bf(v1.w);
    int nb = n >> 7, row = n & 127, kb = k >> 6, c = (k >> 3) & 7;
    *reinterpret_cast<ushort8v*>(
        &wbt[((size_t)nb * KT + kb) * 8192 + row * 64 + ((c ^ (row & 7)) * 8)]) = u;
}

// ---------------------------------------------------------------- att -> bf16, tiled [196][32][128][64] + swizzle.
// Each block streams 128 full 8KB rows sequentially (DRAM-optimal read).
__global__ __launch_bounds__(512) void cvt_att_kernel(
    const float* __restrict__ att, unsigned short* __restrict__ attbf) {
    const int bm = blockIdx.x, t = threadIdx.x;
    const int cl = t & 15;            // 16 threads per row, 512B contiguous each
    const int rb = t >> 4;            // 0..31
    unsigned short* obase = attbf + (size_t)bm * (KT * 8192);
#pragma unroll
    for (int p = 0; p < 4; ++p) {
        int r = p * 32 + rb;
        const float* src = att + (size_t)(bm * 128 + r) * Ff + cl * 128;
        unsigned short* orow = obase + r * 64;
        int swz = r & 7;
#pragma unroll
        for (int jj = 0; jj < 16; ++jj) {
            float4 v0 = *reinterpret_cast<const float4*>(src + jj * 8);
            float4 v1 = *reinterpret_cast<const float4*>(src + jj * 8 + 4);
            ushort8v u;
            u[0]=f2bf(v0.x); u[1]=f2bf(v0.y); u[2]=f2bf(v0.z); u[3]=f2bf(v0.w);
            u[4]=f2bf(v1.x); u[5]=f2bf(v1.y); u[6]=f2bf(v1.z); u[7]=f2bf(v1.w);
            int k = cl * 128 + jj * 8;
            int kb = k >> 6, c = (k >> 3) & 7;
            *reinterpret_cast<ushort8v*>(&orow[kb * 8192 + ((c ^ swz) * 8)]) = u;
        }
    }
}

// ---------------------------------------------------------------- hb = h @ W_hatt^T + b_att + b_hatt   (128 x 512)
__global__ __launch_bounds__(512) void hb_kernel(
    const float* __restrict__ h, const float* __restrict__ W_hatt,
    const float* __restrict__ b_att, const float* __restrict__ b_hatt,
    float* __restrict__ hb) {
    __shared__ float hs[Rr];
    const int b = blockIdx.x, t = threadIdx.x;
    *reinterpret_cast<float2*>(&hs[t * 2]) =
        *reinterpret_cast<const float2*>(&h[(size_t)b * Rr + t * 2]);
    __syncthreads();
    const float* wr = &W_hatt[(size_t)t * Rr];
    float acc = 0.f;
#pragma unroll 4
    for (int k = 0; k < Rr; k += 4) {
        float4 w4 = *reinterpret_cast<const float4*>(&wr[k]);
        acc += w4.x * hs[k] + w4.y * hs[k + 1] + w4.z * hs[k + 2] + w4.w * hs[k + 3];
    }
    hb[(size_t)b * Hh + t] = acc + b_att[t] + b_hatt[t];
}

// ---------------------------------------------------------------- att GEMM + tanh + w_out dot -> scores_part[4][25088]
// Both panels pre-tiled bf16: staging is identity global_load_lds of contiguous 16KB tiles.
__global__ __launch_bounds__(256, 3) void gemmB_kernel(
    const unsigned short* __restrict__ attbf, const unsigned short* __restrict__ wbt,
    const float* __restrict__ hb, const float* __restrict__ w_out,
    float* __restrict__ scores_part) {
    __shared__ __align__(16) unsigned short Asub[8192];
    __shared__ __align__(16) unsigned short Bsub[8192];
    __shared__ float s_red[128];

    const int t = threadIdx.x;
    const int bm = blockIdx.x;            // 0..195
    const int bn = blockIdx.y;            // 0..3
    const int m0 = bm * 128;
    const int wave = t >> 6, lane = t & 63;
    const int l15 = lane & 15, lhi = lane >> 4;
    const int wm = wave >> 1, wn = wave & 1;   // 2x2 waves, 64x64 each

    if (t < 128) s_red[t] = 0.f;

    f32x4 acc[4][4] = {};

    const char* abase = (const char*)(attbf + (size_t)bm * (KT * 8192));
    const char* bbase = (const char*)(wbt   + (size_t)bn * (KT * 8192));
    const int off = wave * 1024 + lane * 16;

    for (int kt = 0; kt < KT; ++kt) {
        __syncthreads();
        const char* ab = abase + kt * 16384;
        const char* bb = bbase + kt * 16384;
#pragma unroll
        for (int i = 0; i < 4; ++i) {
            __builtin_amdgcn_global_load_lds(
                (cas1_void*)(ab + i * 4096 + off),
                (as3_void*)((char*)Asub + i * 4096 + wave * 1024), 16, 0, 0);
            __builtin_amdgcn_global_load_lds(
                (cas1_void*)(bb + i * 4096 + off),
                (as3_void*)((char*)Bsub + i * 4096 + wave * 1024), 16, 0, 0);
        }
        __syncthreads();
#pragma unroll
        for (int kk = 0; kk < 2; ++kk) {
            short8 a[4], b[4];
#pragma unroll
            for (int mi = 0; mi < 4; ++mi) {
                int row = wm * 64 + mi * 16 + l15;
                int ch = (kk * 4 + lhi) ^ (row & 7);
                a[mi] = *reinterpret_cast<const short8*>(&Asub[row * 64 + ch * 8]);
            }
#pragma unroll
            for (int ni = 0; ni < 4; ++ni) {
                int row = wn * 64 + ni * 16 + l15;
                int ch = (kk * 4 + lhi) ^ (row & 7);
                b[ni] = *reinterpret_cast<const short8*>(&Bsub[row * 64 + ch * 8]);
            }
#pragma unroll
            for (int mi = 0; mi < 4; ++mi)
#pragma unroll
                for (int ni = 0; ni < 4; ++ni)
                    acc[mi][ni] = __builtin_amdgcn_mfma_f32_16x16x32_bf16(
                        a[mi], b[ni], acc[mi][ni], 0, 0, 0);
        }
    }

    // epilogue: tanh(C + hb) * w_out, reduce the block's 128 columns
#pragma unroll
    for (int mi = 0; mi < 4; ++mi) {
#pragma unroll
        for (int r = 0; r < 4; ++r) {
            int m_local = wm * 64 + mi * 16 + lhi * 4 + r;
            int m = m0 + m_local;
            int bidx = m / Nn;
            float sum = 0.f;
#pragma unroll
            for (int ni = 0; ni < 4; ++ni) {
                int n = bn * 128 + wn * 64 + ni * 16 + l15;
                float v = acc[mi][ni][r] + hb[(size_t)bidx * Hh + n];
                sum += tanhf(v) * w_out[n];
            }
            sum += __shfl_xor(sum, 1);
            sum += __shfl_xor(sum, 2);
            sum += __shfl_xor(sum, 4);
            sum += __shfl_xor(sum, 8);
            if (l15 == 0) atomicAdd(&s_red[m_local], sum);
        }
    }
    __syncthreads();
    if (t < 128) scores_part[(size_t)blockIdx.y * Mm + m0 + t] = s_red[t];
}

// ---------------------------------------------------------------- softmax over N=196 per batch (sums 4 n-partials)
__global__ void softmax_kernel(const float* __restrict__ sp, float* __restrict__ conv) {
    __shared__ float redm[4];
    __shared__ float reds[4];
    const int b = blockIdx.x, t = threadIdx.x;   // 256 threads
    float s = -1e30f;
    if (t < Nn) {
        size_t i = (size_t)b * Nn + t;
        s = sp[i] + sp[Mm + i] + sp[2 * (size_t)Mm + i] + sp[3 * (size_t)Mm + i];
    }
    float v = s;
#pragma unroll
    for (int o = 1; o < 64; o <<= 1) v = fmaxf(v, __shfl_xor(v, o));
    if ((t & 63) == 0) redm[t >> 6] = v;
    __syncthreads();
    float mx = fmaxf(fmaxf(redm[0], redm[1]), fmaxf(redm[2], redm[3]));
    float e = (t < Nn) ? expf(s - mx) : 0.f;
    float sv = e;
#pragma unroll
    for (int o = 1; o < 64; o <<= 1) sv += __shfl_xor(sv, o);
    if ((t & 63) == 0) reds[t >> 6] = sv;
    __syncthreads();
    float tot = reds[0] + reds[1] + reds[2] + reds[3];
    if (t < Nn) conv[(size_t)b * Nn + t] = e / tot;
}

// ---------------------------------------------------------------- z partials: 7 n-chunks of 28
__global__ __launch_bounds__(256) void zpart_kernel(
    const float* __restrict__ att, const float* __restrict__ conv,
    float* __restrict__ zp) {
    const int fc = blockIdx.x;   // 0..1
    const int b  = blockIdx.y;   // 0..127
    const int ns = blockIdx.z;   // 0..6
    const int t  = threadIdx.x;
    const int f  = fc * 1024 + t * 4;
    const int nbeg = ns * 28;
    const float* ab = &att[((size_t)b * Nn + nbeg) * Ff + f];
    const float* cw = &conv[(size_t)b * Nn + nbeg];
    float4 acc = {0.f, 0.f, 0.f, 0.f};
#pragma unroll 7
    for (int n = 0; n < 28; ++n) {
        float w = cw[n];
        float4 a = *reinterpret_cast<const float4*>(&ab[(size_t)n * Ff]);
        acc.x += w * a.x; acc.y += w * a.y; acc.z += w * a.z; acc.w += w * a.w;
    }
    *reinterpret_cast<float4*>(&zp[((size_t)ns * Bb + b) * Ff + f]) = acc;
}

__global__ void zcomb_kernel(const float* __restrict__ zp, float* __restrict__ z) {
    const size_t i = ((size_t)blockIdx.x * 256 + threadIdx.x) * 4;   // 262144 floats
    float4 o = {0.f, 0.f, 0.f, 0.f};
#pragma unroll
    for (int s = 0; s < 7; ++s) {
        float4 a = *reinterpret_cast<const float4*>(&zp[(size_t)s * 262144 + i]);
        o.x += a.x; o.y += a.y; o.z += a.z; o.w += a.w;
    }
    *reinterpret_cast<float4*>(&z[i]) = o;
}

// ---------------------------------------------------------------- [h|z] -> hi/lo bf16, once
__global__ void cvt_hz_kernel(const float* __restrict__ h, const float* __restrict__ z,
                              unsigned short* __restrict__ hzh, unsigned short* __restrict__ hzl) {
    int i = blockIdx.x * 256 + threadIdx.x;      // 98304 threads -> 384 blocks
    int e = i * 4;
    int row = e / 3072, col = e - row * 3072;
    const float* src = (col < 1024) ? &h[(size_t)row * Rr + col]
                                    : &z[(size_t)row * Ff + (col - 1024)];
    float4 v = *reinterpret_cast<const float4*>(src);
    ushort4 uh, ul;
    uh.x = f2bf(v.x); ul.x = f2bf(v.x - bf2f(uh.x));
    uh.y = f2bf(v.y); ul.y = f2bf(v.y - bf2f(uh.y));
    uh.z = f2bf(v.z); ul.z = f2bf(v.z - bf2f(uh.z));
    uh.w = f2bf(v.w); ul.w = f2bf(v.w - bf2f(uh.w));
    *reinterpret_cast<ushort4*>(&hzh[e]) = uh;
    *reinterpret_cast<ushort4*>(&hzl[e]) = ul;
}

// ---------------------------------------------------------------- LSTM GEMM, K-split x4: S_part[kc] = [h|z]_chunk @ W_chunk^T
__global__ __launch_bounds__(256, 2) void gemm2_kernel(
    const unsigned short* __restrict__ hzh, const unsigned short* __restrict__ hzl,
    const float* __restrict__ Wh2h, const float* __restrict__ Wz2h,
    float* __restrict__ Sp) {
    __shared__ __align__(16) unsigned short Ah[128][72];
    __shared__ __align__(16) unsigned short Al[128][72];
    __shared__ __align__(16) unsigned short Bh[32][72];
    __shared__ __align__(16) unsigned short Bl[32][72];

    const int t = threadIdx.x;
    const int n0 = blockIdx.x * 32;                 // 128 n-blocks
    const int kc = blockIdx.y;                      // 0..3
    const int kbeg = kc * 768;
    const int wave = t >> 6, lane = t & 63;
    const int l15 = lane & 15, lhi = lane >> 4;
    const int wm = wave >> 1, wn = wave & 1;        // wave tile 64M x 16N

    f32x4 acc[4] = {};

    for (int k0 = kbeg; k0 < kbeg + 768; k0 += 64) {
        __syncthreads();
        // stage A: pure bf16 copies
#pragma unroll
        for (int i = 0; i < 4; ++i) {
            int idx = i * 256 + t;
            int row = idx >> 3, k8 = idx & 7;
            *reinterpret_cast<int4*>(&Ah[row][k8 * 8]) =
                *reinterpret_cast<const int4*>(&hzh[(size_t)row * 3072 + k0 + k8 * 8]);
            *reinterpret_cast<int4*>(&Al[row][k8 * 8]) =
                *reinterpret_cast<const int4*>(&hzl[(size_t)row * 3072 + k0 + k8 * 8]);
        }
        // stage B: 32 x 64 fp32 -> hi/lo bf16
        const bool hpart = (k0 < 1024);
#pragma unroll
        for (int i = 0; i < 2; ++i) {
            int idx = i * 256 + t;
            int row = idx >> 4, kq = idx & 15;
            int kg = k0 + kq * 4;
            int n = n0 + row;
            const float* src = hpart ? &Wh2h[(size_t)n * Rr + kg]
                                     : &Wz2h[(size_t)n * Ff + (kg - 1024)];
            float4 v = *reinterpret_cast<const float4*>(src);
            ushort4 uh, ul;
            uh.x = f2bf(v.x); ul.x = f2bf(v.x - bf2f(uh.x));
            uh.y = f2bf(v.y); ul.y = f2bf(v.y - bf2f(uh.y));
            uh.z = f2bf(v.z); ul.z = f2bf(v.z - bf2f(uh.z));
            uh.w = f2bf(v.w); ul.w = f2bf(v.w - bf2f(uh.w));
            *reinterpret_cast<ushort4*>(&Bh[row][kq * 4]) = uh;
            *reinterpret_cast<ushort4*>(&Bl[row][kq * 4]) = ul;
        }
        __syncthreads();
#pragma unroll
        for (int kk = 0; kk < 2; ++kk) {
            short8 bhf = *reinterpret_cast<const short8*>(
                &Bh[wn * 16 + l15][kk * 32 + lhi * 8]);
            short8 blf = *reinterpret_cast<const short8*>(
                &Bl[wn * 16 + l15][kk * 32 + lhi * 8]);
#pragma unroll
            for (int mi = 0; mi < 4; ++mi) {
                short8 ahf = *reinterpret_cast<const short8*>(
                    &Ah[wm * 64 + mi * 16 + l15][kk * 32 + lhi * 8]);
                short8 alf = *reinterpret_cast<const short8*>(
                    &Al[wm * 64 + mi * 16 + l15][kk * 32 + lhi * 8]);
                acc[mi] = __builtin_amdgcn_mfma_f32_16x16x32_bf16(ahf, bhf, acc[mi], 0, 0, 0);
                acc[mi] = __builtin_amdgcn_mfma_f32_16x16x32_bf16(ahf, blf, acc[mi], 0, 0, 0);
                acc[mi] = __builtin_amdgcn_mfma_f32_16x16x32_bf16(alf, bhf, acc[mi], 0, 0, 0);
            }
        }
    }
    const int n = n0 + wn * 16 + l15;
#pragma unroll
    for (int mi = 0; mi < 4; ++mi)
#pragma unroll
        for (int r = 0; r < 4; ++r) {
            int brow = wm * 64 + mi * 16 + lhi * 4 + r;
            Sp[(((size_t)kc * Bb) + brow) * 4096 + n] = acc[mi][r];
        }
}

// ---------------------------------------------------------------- LSTM gates (sums 4 K-partials + biases)
__global__ void lstm_kernel(const float* __restrict__ Sp, const float* __restrict__ c,
                            const float* __restrict__ bh2h, const float* __restrict__ bz2h,
                            float* __restrict__ out) {
    const int t = blockIdx.x * 256 + threadIdx.x;  // 131072
    const int b = t >> 10, r = t & 1023;
    float s0 = 0.f, s1 = 0.f, s2 = 0.f, s3 = 0.f;
#pragma unroll
    for (int kc = 0; kc < 4; ++kc) {
        const float* Sb = &Sp[((size_t)kc * Bb + b) * 4096];
        s0 += Sb[r]; s1 += Sb[1024 + r]; s2 += Sb[2048 + r]; s3 += Sb[3072 + r];
    }
    float ig = sigmf(s0 + bh2h[r] + bz2h[r]);
    float fg = sigmf(s1 + bh2h[1024 + r] + bz2h[1024 + r]);
    float og = sigmf(s2 + bh2h[2048 + r] + bz2h[2048 + r]);
    float gt = tanhf(s3 + bh2h[3072 + r] + bz2h[3072 + r]);
    float nc = fg * c[t] + ig * gt;
    float nh = og * tanhf(nc);
    out[t] = nh;
    out[131072 + t] = nc;
}

// ================================================================ launch
extern "C" void kernel_launch(void* const* d_in, const int* in_sizes, int n_in,
                              void* d_out, int out_size, void* d_ws, size_t ws_size,
                              hipStream_t stream) {
    const float* att     = (const float*)d_in[0];
    const float* h       = (const float*)d_in[3];
    const float* c       = (const float*)d_in[4];
    const float* W_att   = (const float*)d_in[5];
    const float* b_att   = (const float*)d_in[6];
    const float* W_hatt  = (const float*)d_in[7];
    const float* b_hatt  = (const float*)d_in[8];
    const float* w_out   = (const float*)d_in[9];
    const float* W_h2h   = (const float*)d_in[11];
    const float* b_h2h   = (const float*)d_in[12];
    const float* W_z2h   = (const float*)d_in[13];
    const float* b_z2h   = (const float*)d_in[14];
    float* out = (float*)d_out;

    char* ws = (char*)d_ws;
    size_t o = 0;
    unsigned short* attbf = (unsigned short*)(ws + o); o += (size_t)196 * KT * 8192 * 2;  // 102.8 MB
    unsigned short* wbt   = (unsigned short*)(ws + o); o += (size_t)4 * KT * 8192 * 2;    // 2 MB
    float* hb             = (float*)(ws + o);          o += (size_t)Bb * Hh * 4;          // 256 KB
    float* sp             = (float*)(ws + o);          o += (size_t)4 * Mm * 4;           // 400 KB
    float* conv           = (float*)(ws + o);          o += (size_t)Bb * Nn * 4 + 256;    // 100 KB
    float* zp             = (float*)(ws + o);          o += (size_t)7 * Bb * Ff * 4;      // 7.3 MB
    float* z              = (float*)(ws + o);          o += (size_t)Bb * Ff * 4;          // 1 MB
    float* Sp             = (float*)(ws + o);          o += (size_t)4 * Bb * 4096 * 4;    // 8 MB
    unsigned short* hzh   = (unsigned short*)(ws + o); o += (size_t)Bb * 3072 * 2;        // 768 KB
    unsigned short* hzl   = (unsigned short*)(ws + o); o += (size_t)Bb * 3072 * 2;        // 768 KB

    cvt_watt_kernel<<<512, 256, 0, stream>>>(W_att, wbt);
    cvt_att_kernel<<<196, 512, 0, stream>>>(att, attbf);
    hb_kernel<<<Bb, 512, 0, stream>>>(h, W_hatt, b_att, b_hatt, hb);
    gemmB_kernel<<<dim3(196, 4), 256, 0, stream>>>(attbf, wbt, hb, w_out, sp);
    softmax_kernel<<<Bb, 256, 0, stream>>>(sp, conv);
    zpart_kernel<<<dim3(2, Bb, 7), 256, 0, stream>>>(att, conv, zp);
    zcomb_kernel<<<256, 256, 0, stream>>>(zp, z);
    cvt_hz_kernel<<<384, 256, 0, stream>>>(h, z, hzh, hzl);
    gemm2_kernel<<<dim3(128, 4), 256, 0, stream>>>(hzh, hzl, W_h2h, W_z2h, Sp);
    lstm_kernel<<<512, 256, 0, stream>>>(Sp, c, b_h2h, b_z2h, out);
}

// Round 9
// 551.575 us; speedup vs baseline: 1.4539x; 1.1731x over previous
//
#include <hip/hip_runtime.h>
#include <hip/hip_bf16.h>
#include <cstdint>
#include <cstddef>

// Problem constants: B=128, N=196, F=2048, R=1024, H=512
#define Bb   128
#define Nn   196
#define Ff   2048
#define Rr   1024
#define Hh   512
#define Mm   (Bb*Nn)      // 25088
#define KT   32           // K-tiles of 64 in F

using short8   = __attribute__((ext_vector_type(8))) short;
using ushort8v = __attribute__((ext_vector_type(8))) unsigned short;
using f32x4    = __attribute__((ext_vector_type(4))) float;

typedef const __attribute__((address_space(1))) void cas1_void;
typedef __attribute__((address_space(3))) void as3_void;

static __device__ __forceinline__ unsigned short f2bf(float f) {
    unsigned int u = __float_as_uint(f);
    unsigned int r = (u + 0x7FFFu + ((u >> 16) & 1u)) >> 16;
    return (unsigned short)r;
}
static __device__ __forceinline__ float bf2f(unsigned short s) {
    return __uint_as_float(((unsigned int)s) << 16);
}
static __device__ __forceinline__ float sigmf(float x) {
    return 1.0f / (1.0f + expf(-x));
}

// ---------------------------------------------------------------- W_att -> bf16, tiled [4][32][128][64] + chunk-XOR swizzle
__global__ void cvt_watt_kernel(const float* __restrict__ W, unsigned short* __restrict__ wbt) {
    int g = blockIdx.x * 256 + threadIdx.x;   // 131072 threads, 8 cols each
    int n = g >> 8;
    int k = (g & 255) * 8;
    float4 v0 = *reinterpret_cast<const float4*>(&W[(size_t)n * Ff + k]);
    float4 v1 = *reinterpret_cast<const float4*>(&W[(size_t)n * Ff + k + 4]);
    ushort8v u;
    u[0]=f2bf(v0.x); u[1]=f2bf(v0.y); u[2]=f2bf(v0.z); u[3]=f2bf(v0.w);
    u[4]=f2bf(v1.x); u[5]=f2bf(v1.y); u[6]=f2bf(v1.z); u[7]=f2bf(v1.w);
    int nb = n >> 7, row = n & 127, kb = k >> 6, c = (k >> 3) & 7;
    *reinterpret_cast<ushort8v*>(
        &wbt[((size_t)nb * KT + kb) * 8192 + row * 64 + ((c ^ (row & 7)) * 8)]) = u;
}

// ---------------------------------------------------------------- att -> bf16, tile-output-major.
// One block per 16KB tile (bm,kb); writes are lane-consecutive 16B (4KB/iter, no partial lines).
__global__ __launch_bounds__(256) void cvt_att_kernel(
    const float* __restrict__ att, unsigned short* __restrict__ attbf) {
    const int tile = blockIdx.x;             // 196*32 tiles
    const int bm = tile >> 5, kb = tile & 31;
    const int t = threadIdx.x;
    unsigned short* out = attbf + (size_t)tile * 8192;
    const float* abase = att + (size_t)bm * 128 * Ff + kb * 64;
#pragma unroll
    for (int it = 0; it < 4; ++it) {
        int idx = it * 256 + t;              // 0..1023 = row*8 + physchunk
        int row = idx >> 3, p = idx & 7;
        int k = (p ^ (row & 7)) * 8;         // logical chunk for this phys slot
        const float* src = abase + (size_t)row * Ff + k;
        float4 v0 = *reinterpret_cast<const float4*>(src);
        float4 v1 = *reinterpret_cast<const float4*>(src + 4);
        ushort8v u;
        u[0]=f2bf(v0.x); u[1]=f2bf(v0.y); u[2]=f2bf(v0.z); u[3]=f2bf(v0.w);
        u[4]=f2bf(v1.x); u[5]=f2bf(v1.y); u[6]=f2bf(v1.z); u[7]=f2bf(v1.w);
        *reinterpret_cast<ushort8v*>(out + idx * 8) = u;
    }
}

// ---------------------------------------------------------------- hb = h @ W_hatt^T + b_att + b_hatt   (128 x 512)
__global__ __launch_bounds__(512) void hb_kernel(
    const float* __restrict__ h, const float* __restrict__ W_hatt,
    const float* __restrict__ b_att, const float* __restrict__ b_hatt,
    float* __restrict__ hb) {
    __shared__ float hs[Rr];
    const int b = blockIdx.x, t = threadIdx.x;
    *reinterpret_cast<float2*>(&hs[t * 2]) =
        *reinterpret_cast<const float2*>(&h[(size_t)b * Rr + t * 2]);
    __syncthreads();
    const float* wr = &W_hatt[(size_t)t * Rr];
    float acc = 0.f;
#pragma unroll 4
    for (int k = 0; k < Rr; k += 4) {
        float4 w4 = *reinterpret_cast<const float4*>(&wr[k]);
        acc += w4.x * hs[k] + w4.y * hs[k + 1] + w4.z * hs[k + 2] + w4.w * hs[k + 3];
    }
    hb[(size_t)b * Hh + t] = acc + b_att[t] + b_hatt[t];
}

// ---------------------------------------------------------------- att GEMM + tanh + w_out dot -> scores_part[4][25088]
// Grid is (bn=4, bm=196): bn-inner dispatch so the 4 blocks sharing a bm run
// concurrently -> attbf read once from HBM, 3x from L2/L3.
__global__ __launch_bounds__(256, 3) void gemmB_kernel(
    const unsigned short* __restrict__ attbf, const unsigned short* __restrict__ wbt,
    const float* __restrict__ hb, const float* __restrict__ w_out,
    float* __restrict__ scores_part) {
    __shared__ __align__(16) unsigned short Asub[8192];
    __shared__ __align__(16) unsigned short Bsub[8192];
    __shared__ float s_red[128];

    const int t = threadIdx.x;
    const int bn = blockIdx.x;            // 0..3
    const int bm = blockIdx.y;            // 0..195
    const int m0 = bm * 128;
    const int wave = t >> 6, lane = t & 63;
    const int l15 = lane & 15, lhi = lane >> 4;
    const int wm = wave >> 1, wn = wave & 1;   // 2x2 waves, 64x64 each

    if (t < 128) s_red[t] = 0.f;

    f32x4 acc[4][4] = {};

    const char* abase = (const char*)(attbf + (size_t)bm * (KT * 8192));
    const char* bbase = (const char*)(wbt   + (size_t)bn * (KT * 8192));
    const int off = wave * 1024 + lane * 16;

    for (int kt = 0; kt < KT; ++kt) {
        __syncthreads();
        const char* ab = abase + kt * 16384;
        const char* bb = bbase + kt * 16384;
#pragma unroll
        for (int i = 0; i < 4; ++i) {
            __builtin_amdgcn_global_load_lds(
                (cas1_void*)(ab + i * 4096 + off),
                (as3_void*)((char*)Asub + i * 4096 + wave * 1024), 16, 0, 0);
            __builtin_amdgcn_global_load_lds(
                (cas1_void*)(bb + i * 4096 + off),
                (as3_void*)((char*)Bsub + i * 4096 + wave * 1024), 16, 0, 0);
        }
        __syncthreads();
#pragma unroll
        for (int kk = 0; kk < 2; ++kk) {
            short8 a[4], b[4];
#pragma unroll
            for (int mi = 0; mi < 4; ++mi) {
                int row = wm * 64 + mi * 16 + l15;
                int ch = (kk * 4 + lhi) ^ (row & 7);
                a[mi] = *reinterpret_cast<const short8*>(&Asub[row * 64 + ch * 8]);
            }
#pragma unroll
            for (int ni = 0; ni < 4; ++ni) {
                int row = wn * 64 + ni * 16 + l15;
                int ch = (kk * 4 + lhi) ^ (row & 7);
                b[ni] = *reinterpret_cast<const short8*>(&Bsub[row * 64 + ch * 8]);
            }
#pragma unroll
            for (int mi = 0; mi < 4; ++mi)
#pragma unroll
                for (int ni = 0; ni < 4; ++ni)
                    acc[mi][ni] = __builtin_amdgcn_mfma_f32_16x16x32_bf16(
                        a[mi], b[ni], acc[mi][ni], 0, 0, 0);
        }
    }

    // epilogue: tanh(C + hb) * w_out, reduce the block's 128 columns
#pragma unroll
    for (int mi = 0; mi < 4; ++mi) {
#pragma unroll
        for (int r = 0; r < 4; ++r) {
            int m_local = wm * 64 + mi * 16 + lhi * 4 + r;
            int m = m0 + m_local;
            int bidx = m / Nn;
            float sum = 0.f;
#pragma unroll
            for (int ni = 0; ni < 4; ++ni) {
                int n = bn * 128 + wn * 64 + ni * 16 + l15;
                float v = acc[mi][ni][r] + hb[(size_t)bidx * Hh + n];
                sum += tanhf(v) * w_out[n];
            }
            sum += __shfl_xor(sum, 1);
            sum += __shfl_xor(sum, 2);
            sum += __shfl_xor(sum, 4);
            sum += __shfl_xor(sum, 8);
            if (l15 == 0) atomicAdd(&s_red[m_local], sum);
        }
    }
    __syncthreads();
    if (t < 128) scores_part[(size_t)bn * Mm + m0 + t] = s_red[t];
}

// ---------------------------------------------------------------- softmax over N=196 per batch (sums 4 n-partials)
__global__ void softmax_kernel(const float* __restrict__ sp, float* __restrict__ conv) {
    __shared__ float redm[4];
    __shared__ float reds[4];
    const int b = blockIdx.x, t = threadIdx.x;   // 256 threads
    float s = -1e30f;
    if (t < Nn) {
        size_t i = (size_t)b * Nn + t;
        s = sp[i] + sp[Mm + i] + sp[2 * (size_t)Mm + i] + sp[3 * (size_t)Mm + i];
    }
    float v = s;
#pragma unroll
    for (int o = 1; o < 64; o <<= 1) v = fmaxf(v, __shfl_xor(v, o));
    if ((t & 63) == 0) redm[t >> 6] = v;
    __syncthreads();
    float mx = fmaxf(fmaxf(redm[0], redm[1]), fmaxf(redm[2], redm[3]));
    float e = (t < Nn) ? expf(s - mx) : 0.f;
    float sv = e;
#pragma unroll
    for (int o = 1; o < 64; o <<= 1) sv += __shfl_xor(sv, o);
    if ((t & 63) == 0) reds[t >> 6] = sv;
    __syncthreads();
    float tot = reds[0] + reds[1] + reds[2] + reds[3];
    if (t < Nn) conv[(size_t)b * Nn + t] = e / tot;
}

// ---------------------------------------------------------------- z partials from attbf (bf16, half the bytes, L3-warm)
__global__ __launch_bounds__(256) void zpart_kernel(
    const unsigned short* __restrict__ attbf, const float* __restrict__ conv,
    float* __restrict__ zp) {
    const int b  = blockIdx.x;   // 0..127
    const int ns = blockIdx.y;   // 0..6
    const int t  = threadIdx.x;  // f-chunk: f = t*8
    const int kb = t >> 3, c = t & 7;
    const int nbeg = ns * 28;
    const float* cw = &conv[(size_t)b * Nn + nbeg];
    float acc[8] = {};
    for (int n = 0; n < 28; ++n) {
        int m = b * Nn + nbeg + n;
        int bm = m >> 7, row = m & 127;
        const unsigned short* src =
            attbf + ((size_t)(bm * KT + kb)) * 8192 + row * 64 + ((c ^ (row & 7)) * 8);
        ushort8v u = *reinterpret_cast<const ushort8v*>(src);
        float w = cw[n];
#pragma unroll
        for (int j = 0; j < 8; ++j) acc[j] += w * bf2f(u[j]);
    }
    float4 o0 = {acc[0], acc[1], acc[2], acc[3]};
    float4 o1 = {acc[4], acc[5], acc[6], acc[7]};
    float* dst = &zp[((size_t)ns * Bb + b) * Ff + t * 8];
    *reinterpret_cast<float4*>(dst) = o0;
    *reinterpret_cast<float4*>(dst + 4) = o1;
}

__global__ void zcomb_kernel(const float* __restrict__ zp, float* __restrict__ z) {
    const size_t i = ((size_t)blockIdx.x * 256 + threadIdx.x) * 4;   // 262144 floats
    float4 o = {0.f, 0.f, 0.f, 0.f};
#pragma unroll
    for (int s = 0; s < 7; ++s) {
        float4 a = *reinterpret_cast<const float4*>(&zp[(size_t)s * 262144 + i]);
        o.x += a.x; o.y += a.y; o.z += a.z; o.w += a.w;
    }
    *reinterpret_cast<float4*>(&z[i]) = o;
}

// ---------------------------------------------------------------- [h|z] -> hi/lo bf16, once
__global__ void cvt_hz_kernel(const float* __restrict__ h, const float* __restrict__ z,
                              unsigned short* __restrict__ hzh, unsigned short* __restrict__ hzl) {
    int i = blockIdx.x * 256 + threadIdx.x;      // 98304 threads -> 384 blocks
    int e = i * 4;
    int row = e / 3072, col = e - row * 3072;
    const float* src = (col < 1024) ? &h[(size_t)row * Rr + col]
                                    : &z[(size_t)row * Ff + (col - 1024)];
    float4 v = *reinterpret_cast<const float4*>(src);
    ushort4 uh, ul;
    uh.x = f2bf(v.x); ul.x = f2bf(v.x - bf2f(uh.x));
    uh.y = f2bf(v.y); ul.y = f2bf(v.y - bf2f(uh.y));
    uh.z = f2bf(v.z); ul.z = f2bf(v.z - bf2f(uh.z));
    uh.w = f2bf(v.w); ul.w = f2bf(v.w - bf2f(uh.w));
    *reinterpret_cast<ushort4*>(&hzh[e]) = uh;
    *reinterpret_cast<ushort4*>(&hzl[e]) = ul;
}

// ---------------------------------------------------------------- LSTM GEMM, K-split x4: S_part[kc] = [h|z]_chunk @ W_chunk^T
__global__ __launch_bounds__(256, 2) void gemm2_kernel(
    const unsigned short* __restrict__ hzh, const unsigned short* __restrict__ hzl,
    const float* __restrict__ Wh2h, const float* __restrict__ Wz2h,
    float* __restrict__ Sp) {
    __shared__ __align__(16) unsigned short Ah[128][72];
    __shared__ __align__(16) unsigned short Al[128][72];
    __shared__ __align__(16) unsigned short Bh[32][72];
    __shared__ __align__(16) unsigned short Bl[32][72];

    const int t = threadIdx.x;
    const int n0 = blockIdx.x * 32;                 // 128 n-blocks
    const int kc = blockIdx.y;                      // 0..3
    const int kbeg = kc * 768;
    const int wave = t >> 6, lane = t & 63;
    const int l15 = lane & 15, lhi = lane >> 4;
    const int wm = wave >> 1, wn = wave & 1;        // wave tile 64M x 16N

    f32x4 acc[4] = {};

    for (int k0 = kbeg; k0 < kbeg + 768; k0 += 64) {
        __syncthreads();
        // stage A: pure bf16 copies
#pragma unroll
        for (int i = 0; i < 4; ++i) {
            int idx = i * 256 + t;
            int row = idx >> 3, k8 = idx & 7;
            *reinterpret_cast<int4*>(&Ah[row][k8 * 8]) =
                *reinterpret_cast<const int4*>(&hzh[(size_t)row * 3072 + k0 + k8 * 8]);
            *reinterpret_cast<int4*>(&Al[row][k8 * 8]) =
                *reinterpret_cast<const int4*>(&hzl[(size_t)row * 3072 + k0 + k8 * 8]);
        }
        // stage B: 32 x 64 fp32 -> hi/lo bf16
        const bool hpart = (k0 < 1024);
#pragma unroll
        for (int i = 0; i < 2; ++i) {
            int idx = i * 256 + t;
            int row = idx >> 4, kq = idx & 15;
            int kg = k0 + kq * 4;
            int n = n0 + row;
            const float* src = hpart ? &Wh2h[(size_t)n * Rr + kg]
                                     : &Wz2h[(size_t)n * Ff + (kg - 1024)];
            float4 v = *reinterpret_cast<const float4*>(src);
            ushort4 uh, ul;
            uh.x = f2bf(v.x); ul.x = f2bf(v.x - bf2f(uh.x));
            uh.y = f2bf(v.y); ul.y = f2bf(v.y - bf2f(uh.y));
            uh.z = f2bf(v.z); ul.z = f2bf(v.z - bf2f(uh.z));
            uh.w = f2bf(v.w); ul.w = f2bf(v.w - bf2f(uh.w));
            *reinterpret_cast<ushort4*>(&Bh[row][kq * 4]) = uh;
            *reinterpret_cast<ushort4*>(&Bl[row][kq * 4]) = ul;
        }
        __syncthreads();
#pragma unroll
        for (int kk = 0; kk < 2; ++kk) {
            short8 bhf = *reinterpret_cast<const short8*>(
                &Bh[wn * 16 + l15][kk * 32 + lhi * 8]);
            short8 blf = *reinterpret_cast<const short8*>(
                &Bl[wn * 16 + l15][kk * 32 + lhi * 8]);
#pragma unroll
            for (int mi = 0; mi < 4; ++mi) {
                short8 ahf = *reinterpret_cast<const short8*>(
                    &Ah[wm * 64 + mi * 16 + l15][kk * 32 + lhi * 8]);
                short8 alf = *reinterpret_cast<const short8*>(
                    &Al[wm * 64 + mi * 16 + l15][kk * 32 + lhi * 8]);
                acc[mi] = __builtin_amdgcn_mfma_f32_16x16x32_bf16(ahf, bhf, acc[mi], 0, 0, 0);
                acc[mi] = __builtin_amdgcn_mfma_f32_16x16x32_bf16(ahf, blf, acc[mi], 0, 0, 0);
                acc[mi] = __builtin_amdgcn_mfma_f32_16x16x32_bf16(alf, bhf, acc[mi], 0, 0, 0);
            }
        }
    }
    const int n = n0 + wn * 16 + l15;
#pragma unroll
    for (int mi = 0; mi < 4; ++mi)
#pragma unroll
        for (int r = 0; r < 4; ++r) {
            int brow = wm * 64 + mi * 16 + lhi * 4 + r;
            Sp[(((size_t)kc * Bb) + brow) * 4096 + n] = acc[mi][r];
        }
}

// ---------------------------------------------------------------- LSTM gates (sums 4 K-partials + biases)
__global__ void lstm_kernel(const float* __restrict__ Sp, const float* __restrict__ c,
                            const float* __restrict__ bh2h, const float* __restrict__ bz2h,
                            float* __restrict__ out) {
    const int t = blockIdx.x * 256 + threadIdx.x;  // 131072
    const int b = t >> 10, r = t & 1023;
    float s0 = 0.f, s1 = 0.f, s2 = 0.f, s3 = 0.f;
#pragma unroll
    for (int kc = 0; kc < 4; ++kc) {
        const float* Sb = &Sp[((size_t)kc * Bb + b) * 4096];
        s0 += Sb[r]; s1 += Sb[1024 + r]; s2 += Sb[2048 + r]; s3 += Sb[3072 + r];
    }
    float ig = sigmf(s0 + bh2h[r] + bz2h[r]);
    float fg = sigmf(s1 + bh2h[1024 + r] + bz2h[1024 + r]);
    float og = sigmf(s2 + bh2h[2048 + r] + bz2h[2048 + r]);
    float gt = tanhf(s3 + bh2h[3072 + r] + bz2h[3072 + r]);
    float nc = fg * c[t] + ig * gt;
    float nh = og * tanhf(nc);
    out[t] = nh;
    out[131072 + t] = nc;
}

// ================================================================ launch
extern "C" void kernel_launch(void* const* d_in, const int* in_sizes, int n_in,
                              void* d_out, int out_size, void* d_ws, size_t ws_size,
                              hipStream_t stream) {
    const float* att     = (const float*)d_in[0];
    const float* h       = (const float*)d_in[3];
    const float* c       = (const float*)d_in[4];
    const float* W_att   = (const float*)d_in[5];
    const float* b_att   = (const float*)d_in[6];
    const float* W_hatt  = (const float*)d_in[7];
    const float* b_hatt  = (const float*)d_in[8];
    const float* w_out   = (const float*)d_in[9];
    const float* W_h2h   = (const float*)d_in[11];
    const float* b_h2h   = (const float*)d_in[12];
    const float* W_z2h   = (const float*)d_in[13];
    const float* b_z2h   = (const float*)d_in[14];
    float* out = (float*)d_out;

    char* ws = (char*)d_ws;
    size_t o = 0;
    unsigned short* attbf = (unsigned short*)(ws + o); o += (size_t)196 * KT * 8192 * 2;  // 102.8 MB
    unsigned short* wbt   = (unsigned short*)(ws + o); o += (size_t)4 * KT * 8192 * 2;    // 2 MB
    float* hb             = (float*)(ws + o);          o += (size_t)Bb * Hh * 4;          // 256 KB
    float* sp             = (float*)(ws + o);          o += (size_t)4 * Mm * 4;           // 400 KB
    float* conv           = (float*)(ws + o);          o += (size_t)Bb * Nn * 4 + 256;    // 100 KB
    float* zp             = (float*)(ws + o);          o += (size_t)7 * Bb * Ff * 4;      // 7.3 MB
    float* z              = (float*)(ws + o);          o += (size_t)Bb * Ff * 4;          // 1 MB
    float* Sp             = (float*)(ws + o);          o += (size_t)4 * Bb * 4096 * 4;    // 8 MB
    unsigned short* hzh   = (unsigned short*)(ws + o); o += (size_t)Bb * 3072 * 2;        // 768 KB
    unsigned short* hzl   = (unsigned short*)(ws + o); o += (size_t)Bb * 3072 * 2;        // 768 KB

    cvt_watt_kernel<<<512, 256, 0, stream>>>(W_att, wbt);
    cvt_att_kernel<<<196 * KT, 256, 0, stream>>>(att, attbf);
    hb_kernel<<<Bb, 512, 0, stream>>>(h, W_hatt, b_att, b_hatt, hb);
    gemmB_kernel<<<dim3(4, 196), 256, 0, stream>>>(attbf, wbt, hb, w_out, sp);
    softmax_kernel<<<Bb, 256, 0, stream>>>(sp, conv);
    zpart_kernel<<<dim3(Bb, 7), 256, 0, stream>>>(attbf, conv, zp);
    zcomb_kernel<<<256, 256, 0, stream>>>(zp, z);
    cvt_hz_kernel<<<384, 256, 0, stream>>>(h, z, hzh, hzl);
    gemm2_kernel<<<dim3(128, 4), 256, 0, stream>>>(hzh, hzl, W_h2h, W_z2h, Sp);
    lstm_kernel<<<512, 256, 0, stream>>>(Sp, c, b_h2h, b_z2h, out);
}